// Round 1
// baseline (2051.772 us; speedup 1.0000x reference)
//
#include <hip/hip_runtime.h>

// MockTritterModel: embedding -> 8x (ternary linear + residual + LN) -> LN -> ternary head
// Strategy: factor ternary scale out of GEMMs; weights ternarized to bf16 {-1,0,1} (exact);
// activations split hi/lo bf16 so hi@T + lo@T accumulated in f32 MFMA ~= f32 GEMM.
// GEMM = m97-style 128x128x32 tile, global_load_lds(16B) staging, mfma_f32_16x16x32_bf16.

#define H 2048
#define MTOK 2048   // B*S
#define VOC 32000
#define NL 8
#define BM 128
#define BN 128
#define BK 32

typedef __attribute__((ext_vector_type(8))) short bf16x8;
typedef __attribute__((ext_vector_type(4))) float f32x4;

__device__ __forceinline__ unsigned short f2bf(float f) {
  union { float f; unsigned int u; } v; v.f = f;
  unsigned int r = v.u + 0x7fffu + ((v.u >> 16) & 1u);  // RNE
  return (unsigned short)(r >> 16);
}
__device__ __forceinline__ float bf2f(unsigned short u) {
  union { unsigned int u; float f; } v; v.u = ((unsigned int)u) << 16;
  return v.f;
}

// ---------------- abs-sum reduction (for per-tensor mean|w|) ----------------
__global__ void abssum_kernel(const float* __restrict__ w, int n, float* __restrict__ out) {
  __shared__ float sbuf[4];
  int tid = blockIdx.x * blockDim.x + threadIdx.x;
  int stride = gridDim.x * blockDim.x * 4;
  float s = 0.f;
  for (int i = tid * 4; i < n; i += stride) {
    float4 v = *reinterpret_cast<const float4*>(w + i);
    s += fabsf(v.x) + fabsf(v.y) + fabsf(v.z) + fabsf(v.w);
  }
#pragma unroll
  for (int off = 32; off > 0; off >>= 1) s += __shfl_down(s, off);
  if ((threadIdx.x & 63) == 0) sbuf[threadIdx.x >> 6] = s;
  __syncthreads();
  if (threadIdx.x == 0) atomicAdd(out, sbuf[0] + sbuf[1] + sbuf[2] + sbuf[3]);
}

// ---------------- ternarize: T = bf16(clip(round(w/(s+1e-8)),-1,1)) ----------------
__global__ void quantize_kernel(const float* __restrict__ w, int n,
                                const float* __restrict__ sumptr, float cnt,
                                unsigned short* __restrict__ T) {
  float scale = *sumptr / cnt;
  float spe = scale + 1e-8f;
  int tid = blockIdx.x * blockDim.x + threadIdx.x;
  int stride = gridDim.x * blockDim.x * 4;
  for (int i = tid * 4; i < n; i += stride) {
    float4 v = *reinterpret_cast<const float4*>(w + i);
    ushort4 t;
    t.x = f2bf(fminf(fmaxf(rintf(v.x / spe), -1.f), 1.f));
    t.y = f2bf(fminf(fmaxf(rintf(v.y / spe), -1.f), 1.f));
    t.z = f2bf(fminf(fmaxf(rintf(v.z / spe), -1.f), 1.f));
    t.w = f2bf(fminf(fmaxf(rintf(v.w / spe), -1.f), 1.f));
    *reinterpret_cast<ushort4*>(T + i) = t;
  }
}

// ---------------- embedding gather + hi/lo split ----------------
__global__ void gather_split_kernel(const int* __restrict__ ids, const float* __restrict__ embed,
                                    float* __restrict__ h, unsigned short* __restrict__ hi,
                                    unsigned short* __restrict__ lo) {
  int t = blockIdx.x;
  long src = (long)ids[t] * H;
  long dst = (long)t * H;
  for (int c = threadIdx.x * 4; c < H; c += blockDim.x * 4) {
    float4 v = *reinterpret_cast<const float4*>(embed + src + c);
    *reinterpret_cast<float4*>(h + dst + c) = v;
    ushort4 uh, ul;
    uh.x = f2bf(v.x); ul.x = f2bf(v.x - bf2f(uh.x));
    uh.y = f2bf(v.y); ul.y = f2bf(v.y - bf2f(uh.y));
    uh.z = f2bf(v.z); ul.z = f2bf(v.z - bf2f(uh.z));
    uh.w = f2bf(v.w); ul.w = f2bf(v.w - bf2f(uh.w));
    *reinterpret_cast<ushort4*>(hi + dst + c) = uh;
    *reinterpret_cast<ushort4*>(lo + dst + c) = ul;
  }
}

// ---------------- fused (optional residual) + LayerNorm + hi/lo split ----------------
__device__ __forceinline__ float block_sum(float v, float* sbuf) {
#pragma unroll
  for (int off = 32; off > 0; off >>= 1) v += __shfl_down(v, off);
  int lane = threadIdx.x & 63, w = threadIdx.x >> 6;
  if (lane == 0) sbuf[w] = v;
  __syncthreads();
  float r = sbuf[0] + sbuf[1] + sbuf[2] + sbuf[3];
  __syncthreads();  // allow sbuf reuse
  return r;
}

__global__ void ln_kernel(const float* __restrict__ x_in, const float* __restrict__ resid,
                          const float* __restrict__ g, const float* __restrict__ b,
                          float* __restrict__ hout, unsigned short* __restrict__ hi,
                          unsigned short* __restrict__ lo) {
  __shared__ float sbuf[4];
  int t = blockIdx.x;
  long base = (long)t * H;
  int c0 = threadIdx.x * 8;  // 256 threads * 8 = 2048 = H
  float x[8];
#pragma unroll
  for (int j = 0; j < 8; j += 4) {
    float4 v = *reinterpret_cast<const float4*>(x_in + base + c0 + j);
    x[j] = v.x; x[j + 1] = v.y; x[j + 2] = v.z; x[j + 3] = v.w;
  }
  if (resid != nullptr) {
#pragma unroll
    for (int j = 0; j < 8; j += 4) {
      float4 v = *reinterpret_cast<const float4*>(resid + base + c0 + j);
      x[j] += v.x; x[j + 1] += v.y; x[j + 2] += v.z; x[j + 3] += v.w;
    }
  }
  float s = 0.f;
#pragma unroll
  for (int j = 0; j < 8; ++j) s += x[j];
  s = block_sum(s, sbuf);
  float m = s * (1.f / H);
  float vs = 0.f;
#pragma unroll
  for (int j = 0; j < 8; ++j) { float d = x[j] - m; vs += d * d; }
  vs = block_sum(vs, sbuf);
  float r = 1.f / sqrtf(vs * (1.f / H) + 1e-5f);
  float o[8];
#pragma unroll
  for (int j = 0; j < 8; ++j) o[j] = (x[j] - m) * r * g[c0 + j] + b[c0 + j];
  if (hout != nullptr) {
#pragma unroll
    for (int j = 0; j < 8; j += 4) {
      float4 v; v.x = o[j]; v.y = o[j + 1]; v.z = o[j + 2]; v.w = o[j + 3];
      *reinterpret_cast<float4*>(hout + base + c0 + j) = v;
    }
  }
#pragma unroll
  for (int j = 0; j < 8; j += 4) {
    ushort4 uh, ul;
    uh.x = f2bf(o[j]);     ul.x = f2bf(o[j]     - bf2f(uh.x));
    uh.y = f2bf(o[j + 1]); ul.y = f2bf(o[j + 1] - bf2f(uh.y));
    uh.z = f2bf(o[j + 2]); ul.z = f2bf(o[j + 2] - bf2f(uh.z));
    uh.w = f2bf(o[j + 3]); ul.w = f2bf(o[j + 3] - bf2f(uh.w));
    *reinterpret_cast<ushort4*>(hi + base + c0 + j) = uh;
    *reinterpret_cast<ushort4*>(lo + base + c0 + j) = ul;
  }
}

// ---------------- GEMM: C[m,n] = scale * sum_k (Ahi+Alo)[m,k] * Bt[n,k] (+ bias[n]) ----------------
__device__ __forceinline__ void gll16(const void* g, void* l) {
  __builtin_amdgcn_global_load_lds((const __attribute__((address_space(1))) void*)g,
                                   (__attribute__((address_space(3))) void*)l, 16, 0, 0);
}

// stage a [128][32] bf16 tile (8 KiB): 256 threads, 2 x 16B global_load_lds each
__device__ __forceinline__ void stage_tile(unsigned short* sdst, const unsigned short* G,
                                           long row0, int k0, int ldk, int tid) {
  int w = tid >> 6, lane = tid & 63;
#pragma unroll
  for (int i = 0; i < 2; ++i) {
    int blk = i * 4 + w;             // 8 x 1024B blocks
    int s = blk * 64 + lane;         // 16B segment id
    int row = s >> 2, col = (s & 3) * 8;
    const unsigned short* g = G + (row0 + row) * (long)ldk + (k0 + col);
    gll16((const void*)g, (void*)(sdst + blk * 512));  // 512 ushorts = 1024 B
  }
}

template <bool HAS_BIAS>
__global__ __launch_bounds__(256)
void gemm_bt(const unsigned short* __restrict__ Ahi, const unsigned short* __restrict__ Alo,
             const unsigned short* __restrict__ Bt, const float* __restrict__ bias,
             const float* __restrict__ sumptr, float cnt,
             float* __restrict__ C, int N, int K) {
  __shared__ unsigned short sAhi[BM * BK];
  __shared__ unsigned short sAlo[BM * BK];
  __shared__ unsigned short sB[BN * BK];
  int tid = threadIdx.x;
  int lane = tid & 63, wid = tid >> 6;
  int wr = wid >> 1, wc = wid & 1;           // 2x2 waves -> 64x64 each
  long row0 = (long)blockIdx.y * BM;
  long col0 = (long)blockIdx.x * BN;

  f32x4 acc[4][4] = {};

  for (int k0 = 0; k0 < K; k0 += BK) {
    stage_tile(sAhi, Ahi, row0, k0, K, tid);
    stage_tile(sAlo, Alo, row0, k0, K, tid);
    stage_tile(sB, Bt, col0, k0, K, tid);
    __syncthreads();  // compiler emits vmcnt(0) drain before barrier

    bf16x8 ah[4], al[4], bb[4];
    int kb = (lane >> 4) * 8;
    int rsel = lane & 15;
#pragma unroll
    for (int f = 0; f < 4; ++f) {
      int ra = wr * 64 + f * 16 + rsel;
      ah[f] = *reinterpret_cast<const bf16x8*>(&sAhi[ra * BK + kb]);
      al[f] = *reinterpret_cast<const bf16x8*>(&sAlo[ra * BK + kb]);
      int rb = wc * 64 + f * 16 + rsel;
      bb[f] = *reinterpret_cast<const bf16x8*>(&sB[rb * BK + kb]);
    }
#pragma unroll
    for (int mf = 0; mf < 4; ++mf)
#pragma unroll
      for (int nf = 0; nf < 4; ++nf) {
        acc[mf][nf] = __builtin_amdgcn_mfma_f32_16x16x32_bf16(ah[mf], bb[nf], acc[mf][nf], 0, 0, 0);
        acc[mf][nf] = __builtin_amdgcn_mfma_f32_16x16x32_bf16(al[mf], bb[nf], acc[mf][nf], 0, 0, 0);
      }
    __syncthreads();
  }

  float scale = *sumptr / cnt;
#pragma unroll
  for (int mf = 0; mf < 4; ++mf) {
    long grow0 = row0 + wr * 64 + mf * 16 + (lane >> 4) * 4;
#pragma unroll
    for (int nf = 0; nf < 4; ++nf) {
      long gcol = col0 + wc * 64 + nf * 16 + (lane & 15);
      float bv = HAS_BIAS ? bias[gcol] : 0.f;
#pragma unroll
      for (int r = 0; r < 4; ++r) {
        C[(grow0 + r) * (long)N + gcol] = acc[mf][nf][r] * scale + bv;
      }
    }
  }
}

// ---------------- launch ----------------
extern "C" void kernel_launch(void* const* d_in, const int* in_sizes, int n_in,
                              void* d_out, int out_size, void* d_ws, size_t ws_size,
                              hipStream_t stream) {
  const int* input_ids = (const int*)d_in[0];
  const float* embed   = (const float*)d_in[1];
  const float* layer_w = (const float*)d_in[2];
  const float* layer_b = (const float*)d_in[3];
  const float* ln_g    = (const float*)d_in[4];
  const float* ln_b    = (const float*)d_in[5];
  const float* final_g = (const float*)d_in[6];
  const float* final_b = (const float*)d_in[7];
  const float* head_w  = (const float*)d_in[8];
  float* out = (float*)d_out;

  char* ws = (char*)d_ws;
  size_t off = 0;
  auto take = [&](size_t bytes) -> void* {
    void* p = ws + off;
    off = (off + bytes + 255) & ~(size_t)255;
    return p;
  };
  float* sums            = (float*)take(16 * sizeof(float));          // [0..7]=layers, [8]=head
  unsigned short* Tl     = (unsigned short*)take((size_t)H * H * 2);  // reused per layer
  unsigned short* Th     = (unsigned short*)take((size_t)VOC * H * 2);
  float* hbuf            = (float*)take((size_t)MTOK * H * 4);
  float* ybuf            = (float*)take((size_t)MTOK * H * 4);
  unsigned short* hi     = (unsigned short*)take((size_t)MTOK * H * 2);
  unsigned short* lo     = (unsigned short*)take((size_t)MTOK * H * 2);
  (void)ws_size; (void)in_sizes; (void)n_in; (void)out_size;

  hipMemsetAsync(sums, 0, 16 * sizeof(float), stream);

  for (int l = 0; l < NL; ++l)
    abssum_kernel<<<512, 256, 0, stream>>>(layer_w + (size_t)l * H * H, H * H, sums + l);
  abssum_kernel<<<2048, 256, 0, stream>>>(head_w, VOC * H, sums + 8);

  quantize_kernel<<<4096, 256, 0, stream>>>(head_w, VOC * H, sums + 8, (float)((size_t)VOC * H), Th);

  gather_split_kernel<<<MTOK, 256, 0, stream>>>(input_ids, embed, hbuf, hi, lo);

  for (int l = 0; l < NL; ++l) {
    quantize_kernel<<<1024, 256, 0, stream>>>(layer_w + (size_t)l * H * H, H * H, sums + l,
                                              (float)(H * H), Tl);
    gemm_bt<true><<<dim3(H / BN, MTOK / BM), 256, 0, stream>>>(
        hi, lo, Tl, layer_b + (size_t)l * H, sums + l, (float)(H * H), ybuf, H, H);
    ln_kernel<<<MTOK, 256, 0, stream>>>(ybuf, hbuf, ln_g + (size_t)l * H, ln_b + (size_t)l * H,
                                        hbuf, hi, lo);
  }

  ln_kernel<<<MTOK, 256, 0, stream>>>(hbuf, nullptr, final_g, final_b, nullptr, hi, lo);

  gemm_bt<false><<<dim3(VOC / BN, MTOK / BM), 256, 0, stream>>>(
      hi, lo, Th, nullptr, sums + 8, (float)((size_t)VOC * H), out, VOC, H);
}

// Round 2
// 1581.342 us; speedup vs baseline: 1.2975x; 1.2975x over previous
//
#include <hip/hip_runtime.h>

// MockTritterModel: embedding -> 8x (ternary linear + residual + LN) -> LN -> ternary head
// Round 2: fp16 activations single-pass (ternary weights exact in fp16; only activation
// rounding at 2^-11 -> ~3e-4 logit error). Layer GEMM 128x64 tile (512 blocks, 2/CU).
// Head GEMM row-fastest block order + XCD swizzle for L2 retention of A.

#define H 2048
#define MTOK 2048   // B*S
#define VOC 32000
#define NL 8
#define BK 32

typedef __attribute__((ext_vector_type(8))) _Float16 f16x8;
typedef __attribute__((ext_vector_type(4))) float f32x4;

__device__ __forceinline__ unsigned short f2h(float f) {
  _Float16 h = (_Float16)f;  // v_cvt_f16_f32, RNE
  union { _Float16 h; unsigned short u; } v; v.h = h;
  return v.u;
}

// ---------------- abs-sum reduction (for per-tensor mean|w|) ----------------
__global__ void abssum_kernel(const float* __restrict__ w, int n, float* __restrict__ out) {
  __shared__ float sbuf[4];
  int tid = blockIdx.x * blockDim.x + threadIdx.x;
  int stride = gridDim.x * blockDim.x * 4;
  float s = 0.f;
  for (int i = tid * 4; i < n; i += stride) {
    float4 v = *reinterpret_cast<const float4*>(w + i);
    s += fabsf(v.x) + fabsf(v.y) + fabsf(v.z) + fabsf(v.w);
  }
#pragma unroll
  for (int off = 32; off > 0; off >>= 1) s += __shfl_down(s, off);
  if ((threadIdx.x & 63) == 0) sbuf[threadIdx.x >> 6] = s;
  __syncthreads();
  if (threadIdx.x == 0) atomicAdd(out, sbuf[0] + sbuf[1] + sbuf[2] + sbuf[3]);
}

// ---------------- ternarize: T = fp16(clip(round(w/(s+1e-8)),-1,1)) ----------------
__global__ void quantize_kernel(const float* __restrict__ w, int n,
                                const float* __restrict__ sumptr, float cnt,
                                unsigned short* __restrict__ T) {
  float scale = *sumptr / cnt;
  float spe = scale + 1e-8f;
  int tid = blockIdx.x * blockDim.x + threadIdx.x;
  int stride = gridDim.x * blockDim.x * 4;
  for (int i = tid * 4; i < n; i += stride) {
    float4 v = *reinterpret_cast<const float4*>(w + i);
    ushort4 t;
    t.x = f2h(fminf(fmaxf(rintf(v.x / spe), -1.f), 1.f));
    t.y = f2h(fminf(fmaxf(rintf(v.y / spe), -1.f), 1.f));
    t.z = f2h(fminf(fmaxf(rintf(v.z / spe), -1.f), 1.f));
    t.w = f2h(fminf(fmaxf(rintf(v.w / spe), -1.f), 1.f));
    *reinterpret_cast<ushort4*>(T + i) = t;
  }
}

// ---------------- embedding gather + fp16 cast ----------------
__global__ void gather_split_kernel(const int* __restrict__ ids, const float* __restrict__ embed,
                                    float* __restrict__ h, unsigned short* __restrict__ act) {
  int t = blockIdx.x;
  long src = (long)ids[t] * H;
  long dst = (long)t * H;
  for (int c = threadIdx.x * 4; c < H; c += blockDim.x * 4) {
    float4 v = *reinterpret_cast<const float4*>(embed + src + c);
    *reinterpret_cast<float4*>(h + dst + c) = v;
    ushort4 u;
    u.x = f2h(v.x); u.y = f2h(v.y); u.z = f2h(v.z); u.w = f2h(v.w);
    *reinterpret_cast<ushort4*>(act + dst + c) = u;
  }
}

// ---------------- fused (optional residual) + LayerNorm + fp16 cast ----------------
__device__ __forceinline__ float block_sum(float v, float* sbuf) {
#pragma unroll
  for (int off = 32; off > 0; off >>= 1) v += __shfl_down(v, off);
  int lane = threadIdx.x & 63, w = threadIdx.x >> 6;
  if (lane == 0) sbuf[w] = v;
  __syncthreads();
  float r = sbuf[0] + sbuf[1] + sbuf[2] + sbuf[3];
  __syncthreads();
  return r;
}

__global__ void ln_kernel(const float* __restrict__ x_in, const float* __restrict__ resid,
                          const float* __restrict__ g, const float* __restrict__ b,
                          float* __restrict__ hout, unsigned short* __restrict__ act) {
  __shared__ float sbuf[4];
  int t = blockIdx.x;
  long base = (long)t * H;
  int c0 = threadIdx.x * 8;  // 256 threads * 8 = 2048 = H
  float x[8];
#pragma unroll
  for (int j = 0; j < 8; j += 4) {
    float4 v = *reinterpret_cast<const float4*>(x_in + base + c0 + j);
    x[j] = v.x; x[j + 1] = v.y; x[j + 2] = v.z; x[j + 3] = v.w;
  }
  if (resid != nullptr) {
#pragma unroll
    for (int j = 0; j < 8; j += 4) {
      float4 v = *reinterpret_cast<const float4*>(resid + base + c0 + j);
      x[j] += v.x; x[j + 1] += v.y; x[j + 2] += v.z; x[j + 3] += v.w;
    }
  }
  float s = 0.f;
#pragma unroll
  for (int j = 0; j < 8; ++j) s += x[j];
  s = block_sum(s, sbuf);
  float m = s * (1.f / H);
  float vs = 0.f;
#pragma unroll
  for (int j = 0; j < 8; ++j) { float d = x[j] - m; vs += d * d; }
  vs = block_sum(vs, sbuf);
  float r = 1.f / sqrtf(vs * (1.f / H) + 1e-5f);
  float o[8];
#pragma unroll
  for (int j = 0; j < 8; ++j) o[j] = (x[j] - m) * r * g[c0 + j] + b[c0 + j];
  if (hout != nullptr) {
#pragma unroll
    for (int j = 0; j < 8; j += 4) {
      float4 v; v.x = o[j]; v.y = o[j + 1]; v.z = o[j + 2]; v.w = o[j + 3];
      *reinterpret_cast<float4*>(hout + base + c0 + j) = v;
    }
  }
#pragma unroll
  for (int j = 0; j < 8; j += 4) {
    ushort4 u;
    u.x = f2h(o[j]); u.y = f2h(o[j + 1]); u.z = f2h(o[j + 2]); u.w = f2h(o[j + 3]);
    *reinterpret_cast<ushort4*>(act + base + c0 + j) = u;
  }
}

// ---------------- GEMM: C[m,n] = scale * sum_k A[m,k] * Bt[n,k] (+ bias[n]) ----------------
__device__ __forceinline__ void gll16(const void* g, void* l) {
  __builtin_amdgcn_global_load_lds((const __attribute__((address_space(1))) void*)g,
                                   (__attribute__((address_space(3))) void*)l, 16, 0, 0);
}

// stage a [ROWS][32] fp16 tile: 256 threads, ROWS/64 x 16B global_load_lds each
template <int ROWS>
__device__ __forceinline__ void stage_tile(unsigned short* sdst, const unsigned short* G,
                                           long row0, int k0, long ldk, int tid) {
#pragma unroll
  for (int i = 0; i < ROWS / 64; ++i) {
    int blk = i * 4 + (tid >> 6);
    int s = blk * 64 + (tid & 63);
    int row = s >> 2, col = (s & 3) * 8;
    const unsigned short* g = G + (row0 + row) * ldk + (k0 + col);
    gll16((const void*)g, (void*)(sdst + blk * 512));  // linear dest: blk*1024B + lane*16B
  }
}

// TBM x TBN tile, 4 waves laid out WR x WC, each wave MF*16 x NF*16 output.
template <int TBM, int TBN, int WR, int WC, int MF, int NF, bool HAS_BIAS>
__global__ __launch_bounds__(256)
void gemm_t(const unsigned short* __restrict__ A, const unsigned short* __restrict__ Bt,
            const float* __restrict__ bias, const float* __restrict__ sumptr, float cnt,
            float* __restrict__ C, int N, int K, int nrb) {
  __shared__ unsigned short sA[TBM * BK];
  __shared__ unsigned short sB[TBN * BK];
  int tid = threadIdx.x;
  int lane = tid & 63, wid = tid >> 6;
  int wr = wid / WC, wc = wid % WC;

  // XCD-aware swizzle (grid size is a multiple of 8), then row-block-fastest mapping:
  // consecutive swizzled bids share the B column-tile; each XCD chunk re-reads all of A (L2-fits).
  int nwg = gridDim.x;
  int bid = blockIdx.x;
  int chunk = nwg >> 3;
  int swz = (bid & 7) * chunk + (bid >> 3);
  int rb = swz % nrb, cb = swz / nrb;
  long row0 = (long)rb * TBM;
  long col0 = (long)cb * TBN;

  f32x4 acc[MF][NF] = {};

  for (int k0 = 0; k0 < K; k0 += BK) {
    stage_tile<TBM>(sA, A, row0, k0, K, tid);
    stage_tile<TBN>(sB, Bt, col0, k0, K, tid);
    __syncthreads();

    f16x8 af[MF], bf[NF];
    int kb = (lane >> 4) * 8;
    int rsel = lane & 15;
#pragma unroll
    for (int f = 0; f < MF; ++f) {
      int ra = wr * (MF * 16) + f * 16 + rsel;
      af[f] = *reinterpret_cast<const f16x8*>(&sA[ra * BK + kb]);
    }
#pragma unroll
    for (int f = 0; f < NF; ++f) {
      int rbn = wc * (NF * 16) + f * 16 + rsel;
      bf[f] = *reinterpret_cast<const f16x8*>(&sB[rbn * BK + kb]);
    }
#pragma unroll
    for (int mf = 0; mf < MF; ++mf)
#pragma unroll
      for (int nf = 0; nf < NF; ++nf)
        acc[mf][nf] = __builtin_amdgcn_mfma_f32_16x16x32_f16(af[mf], bf[nf], acc[mf][nf], 0, 0, 0);
    __syncthreads();
  }

  float scale = *sumptr / cnt;
#pragma unroll
  for (int mf = 0; mf < MF; ++mf) {
    long grow0 = row0 + wr * (MF * 16) + mf * 16 + (lane >> 4) * 4;
#pragma unroll
    for (int nf = 0; nf < NF; ++nf) {
      long gcol = col0 + wc * (NF * 16) + nf * 16 + (lane & 15);
      float bv = HAS_BIAS ? bias[gcol] : 0.f;
#pragma unroll
      for (int r = 0; r < 4; ++r) {
        C[(grow0 + r) * (long)N + gcol] = acc[mf][nf][r] * scale + bv;
      }
    }
  }
}

// ---------------- launch ----------------
extern "C" void kernel_launch(void* const* d_in, const int* in_sizes, int n_in,
                              void* d_out, int out_size, void* d_ws, size_t ws_size,
                              hipStream_t stream) {
  const int* input_ids = (const int*)d_in[0];
  const float* embed   = (const float*)d_in[1];
  const float* layer_w = (const float*)d_in[2];
  const float* layer_b = (const float*)d_in[3];
  const float* ln_g    = (const float*)d_in[4];
  const float* ln_b    = (const float*)d_in[5];
  const float* final_g = (const float*)d_in[6];
  const float* final_b = (const float*)d_in[7];
  const float* head_w  = (const float*)d_in[8];
  float* out = (float*)d_out;

  char* ws = (char*)d_ws;
  size_t off = 0;
  auto take = [&](size_t bytes) -> void* {
    void* p = ws + off;
    off = (off + bytes + 255) & ~(size_t)255;
    return p;
  };
  float* sums        = (float*)take(16 * sizeof(float));          // [0..7]=layers, [8]=head
  unsigned short* Tl = (unsigned short*)take((size_t)H * H * 2);  // reused per layer
  unsigned short* Th = (unsigned short*)take((size_t)VOC * H * 2);
  float* hbuf        = (float*)take((size_t)MTOK * H * 4);
  float* ybuf        = (float*)take((size_t)MTOK * H * 4);
  unsigned short* act = (unsigned short*)take((size_t)MTOK * H * 2);
  (void)ws_size; (void)in_sizes; (void)n_in; (void)out_size;

  hipMemsetAsync(sums, 0, 16 * sizeof(float), stream);

  for (int l = 0; l < NL; ++l)
    abssum_kernel<<<512, 256, 0, stream>>>(layer_w + (size_t)l * H * H, H * H, sums + l);
  abssum_kernel<<<2048, 256, 0, stream>>>(head_w, VOC * H, sums + 8);

  quantize_kernel<<<4096, 256, 0, stream>>>(head_w, VOC * H, sums + 8, (float)((size_t)VOC * H), Th);

  gather_split_kernel<<<MTOK, 256, 0, stream>>>(input_ids, embed, hbuf, act);

  for (int l = 0; l < NL; ++l) {
    quantize_kernel<<<1024, 256, 0, stream>>>(layer_w + (size_t)l * H * H, H * H, sums + l,
                                              (float)(H * H), Tl);
    // 128x64 tile: grid = (2048/128)*(2048/64) = 512 blocks = 2/CU
    gemm_t<128, 64, 4, 1, 2, 4, true><<<512, 256, 0, stream>>>(
        act, Tl, layer_b + (size_t)l * H, sums + l, (float)(H * H), ybuf, H, H, MTOK / 128);
    ln_kernel<<<MTOK, 256, 0, stream>>>(ybuf, hbuf, ln_g + (size_t)l * H, ln_b + (size_t)l * H,
                                        hbuf, act);
  }

  ln_kernel<<<MTOK, 256, 0, stream>>>(hbuf, nullptr, final_g, final_b, nullptr, act);

  // head: 128x128 tile: grid = (2048/128)*(32000/128) = 16*250 = 4000 blocks
  gemm_t<128, 128, 2, 2, 4, 4, false><<<4000, 256, 0, stream>>>(
      act, Th, nullptr, sums + 8, (float)((size_t)VOC * H), out, VOC, H, MTOK / 128);
}

// Round 3
// 1478.230 us; speedup vs baseline: 1.3880x; 1.0698x over previous
//
#include <hip/hip_runtime.h>

// MockTritterModel: embedding -> 8x (ternary linear + residual + LN) -> LN -> ternary head
// Round 3: 2-phase double-buffered GEMM (T3-minimum), BK=64, both-sides XOR seg swizzle
// (linear LDS dest + inverse-swizzled global source for global_load_lds, same XOR on ds_read).
// fp16 activations, ternary weights exact in fp16. Numerics identical to round 2.

#define H 2048
#define MTOK 2048   // B*S
#define VOC 32000
#define NL 8
#define BK 64       // fp16 elems per K-tile (128 B per row)

typedef __attribute__((ext_vector_type(8))) _Float16 f16x8;
typedef __attribute__((ext_vector_type(4))) float f32x4;

__device__ __forceinline__ unsigned short f2h(float f) {
  _Float16 h = (_Float16)f;  // v_cvt_f16_f32, RNE
  union { _Float16 h; unsigned short u; } v; v.h = h;
  return v.u;
}

// ---------------- abs-sum reduction (for per-tensor mean|w|) ----------------
// gridDim.y selects the tensor (stride nstride between tensors); out[y] += partial.
__global__ void abssum_kernel(const float* __restrict__ w, int n, long nstride,
                              float* __restrict__ out) {
  __shared__ float sbuf[4];
  const float* wp = w + (long)blockIdx.y * nstride;
  int tid = blockIdx.x * blockDim.x + threadIdx.x;
  int stride = gridDim.x * blockDim.x * 4;
  float s = 0.f;
  for (int i = tid * 4; i < n; i += stride) {
    float4 v = *reinterpret_cast<const float4*>(wp + i);
    s += fabsf(v.x) + fabsf(v.y) + fabsf(v.z) + fabsf(v.w);
  }
#pragma unroll
  for (int off = 32; off > 0; off >>= 1) s += __shfl_down(s, off);
  if ((threadIdx.x & 63) == 0) sbuf[threadIdx.x >> 6] = s;
  __syncthreads();
  if (threadIdx.x == 0) atomicAdd(out + blockIdx.y, sbuf[0] + sbuf[1] + sbuf[2] + sbuf[3]);
}

// ---------------- ternarize: T = fp16(clip(round(w/(s+1e-8)),-1,1)) ----------------
__global__ void quantize_kernel(const float* __restrict__ w, int n,
                                const float* __restrict__ sumptr, float cnt,
                                unsigned short* __restrict__ T) {
  float scale = *sumptr / cnt;
  float spe = scale + 1e-8f;
  int tid = blockIdx.x * blockDim.x + threadIdx.x;
  int stride = gridDim.x * blockDim.x * 4;
  for (int i = tid * 4; i < n; i += stride) {
    float4 v = *reinterpret_cast<const float4*>(w + i);
    ushort4 t;
    t.x = f2h(fminf(fmaxf(rintf(v.x / spe), -1.f), 1.f));
    t.y = f2h(fminf(fmaxf(rintf(v.y / spe), -1.f), 1.f));
    t.z = f2h(fminf(fmaxf(rintf(v.z / spe), -1.f), 1.f));
    t.w = f2h(fminf(fmaxf(rintf(v.w / spe), -1.f), 1.f));
    *reinterpret_cast<ushort4*>(T + i) = t;
  }
}

// ---------------- embedding gather + fp16 cast ----------------
__global__ void gather_split_kernel(const int* __restrict__ ids, const float* __restrict__ embed,
                                    float* __restrict__ h, unsigned short* __restrict__ act) {
  int t = blockIdx.x;
  long src = (long)ids[t] * H;
  long dst = (long)t * H;
  for (int c = threadIdx.x * 4; c < H; c += blockDim.x * 4) {
    float4 v = *reinterpret_cast<const float4*>(embed + src + c);
    *reinterpret_cast<float4*>(h + dst + c) = v;
    ushort4 u;
    u.x = f2h(v.x); u.y = f2h(v.y); u.z = f2h(v.z); u.w = f2h(v.w);
    *reinterpret_cast<ushort4*>(act + dst + c) = u;
  }
}

// ---------------- fused (optional residual) + LayerNorm + fp16 cast ----------------
__device__ __forceinline__ float block_sum(float v, float* sbuf) {
#pragma unroll
  for (int off = 32; off > 0; off >>= 1) v += __shfl_down(v, off);
  int lane = threadIdx.x & 63, w = threadIdx.x >> 6;
  if (lane == 0) sbuf[w] = v;
  __syncthreads();
  float r = sbuf[0] + sbuf[1] + sbuf[2] + sbuf[3];
  __syncthreads();
  return r;
}

__global__ void ln_kernel(const float* __restrict__ x_in, const float* __restrict__ resid,
                          const float* __restrict__ g, const float* __restrict__ b,
                          float* __restrict__ hout, unsigned short* __restrict__ act) {
  __shared__ float sbuf[4];
  int t = blockIdx.x;
  long base = (long)t * H;
  int c0 = threadIdx.x * 8;  // 256 threads * 8 = 2048 = H
  float x[8];
#pragma unroll
  for (int j = 0; j < 8; j += 4) {
    float4 v = *reinterpret_cast<const float4*>(x_in + base + c0 + j);
    x[j] = v.x; x[j + 1] = v.y; x[j + 2] = v.z; x[j + 3] = v.w;
  }
  if (resid != nullptr) {
#pragma unroll
    for (int j = 0; j < 8; j += 4) {
      float4 v = *reinterpret_cast<const float4*>(resid + base + c0 + j);
      x[j] += v.x; x[j + 1] += v.y; x[j + 2] += v.z; x[j + 3] += v.w;
    }
  }
  float s = 0.f;
#pragma unroll
  for (int j = 0; j < 8; ++j) s += x[j];
  s = block_sum(s, sbuf);
  float m = s * (1.f / H);
  float vs = 0.f;
#pragma unroll
  for (int j = 0; j < 8; ++j) { float d = x[j] - m; vs += d * d; }
  vs = block_sum(vs, sbuf);
  float r = 1.f / sqrtf(vs * (1.f / H) + 1e-5f);
  float o[8];
#pragma unroll
  for (int j = 0; j < 8; ++j) o[j] = (x[j] - m) * r * g[c0 + j] + b[c0 + j];
  if (hout != nullptr) {
#pragma unroll
    for (int j = 0; j < 8; j += 4) {
      float4 v; v.x = o[j]; v.y = o[j + 1]; v.z = o[j + 2]; v.w = o[j + 3];
      *reinterpret_cast<float4*>(hout + base + c0 + j) = v;
    }
  }
#pragma unroll
  for (int j = 0; j < 8; j += 4) {
    ushort4 u;
    u.x = f2h(o[j]); u.y = f2h(o[j + 1]); u.z = f2h(o[j + 2]); u.w = f2h(o[j + 3]);
    *reinterpret_cast<ushort4*>(act + base + c0 + j) = u;
  }
}

// ---------------- GEMM: C[m,n] = scale * sum_k A[m,k] * Bt[n,k] (+ bias[n]) ----------------
__device__ __forceinline__ void gll16(const void* g, void* l) {
  __builtin_amdgcn_global_load_lds((const __attribute__((address_space(1))) void*)g,
                                   (__attribute__((address_space(3))) void*)l, 16, 0, 0);
}

// Stage a [ROWS][64] fp16 tile (ROWS*128 bytes) into linear LDS, with the global SOURCE
// seg index pre-XOR-swizzled (rule #21: linear dest, inverse-swz source, swz on read).
// LDS slot (row, c) holds global seg (row, c ^ (row & 7)).
template <int ROWS>
__device__ __forceinline__ void stage_tile(unsigned short* sdst, const unsigned short* G,
                                           long row0, int k0, long ldk, int tid) {
  int wv = tid >> 6, lane = tid & 63;
  int c = lane & 7;            // seg slot within row (8 x 16B per 128B row)
  int r8 = lane >> 3;          // row within 8-row block
  int cs = c ^ r8;             // swizzled source seg
#pragma unroll
  for (int i = 0; i < ROWS / 32; ++i) {
    int blk = i * 4 + wv;                 // 1 KiB LDS blocks, 8 rows each
    int row = blk * 8 + r8;
    const unsigned short* g = G + (row0 + row) * ldk + (k0 + cs * 8);
    gll16((const void*)g, (void*)(sdst + blk * 512));  // lane writes blk*1024B + lane*16B
  }
}

// TBM x TBN tile, 4 waves laid out WR x WC, each wave (MF*16) x (NF*16) output, BK=64, 2-phase.
template <int TBM, int TBN, int WR, int WC, int MF, int NF, bool HAS_BIAS>
__global__ __launch_bounds__(256)
void gemm_t(const unsigned short* __restrict__ A, const unsigned short* __restrict__ Bt,
            const float* __restrict__ bias, const float* __restrict__ sumptr, float cnt,
            float* __restrict__ C, int N, int K, int nrb) {
  __shared__ unsigned short sA[2][TBM * BK];
  __shared__ unsigned short sB[2][TBN * BK];
  int tid = threadIdx.x;
  int lane = tid & 63, wid = tid >> 6;
  int wr = wid / WC, wc = wid % WC;

  // XCD-aware bijective swizzle (grid % 8 == 0), then row-block-fastest mapping.
  int nwg = gridDim.x;
  int bid = blockIdx.x;
  int chunk = nwg >> 3;
  int swz = (bid & 7) * chunk + (bid >> 3);
  int rb = swz % nrb, cbl = swz / nrb;
  long row0 = (long)rb * TBM;
  long col0 = (long)cbl * TBN;

  f32x4 acc[MF][NF] = {};

  int rsel = lane & 15;
  int hi = lane >> 4;          // 0..3
  int lx = lane & 7;           // read-side XOR key (row & 7 == lane & 7 for 16-row frags)

  int NT = K >> 6;             // K / BK
  stage_tile<TBM>(sA[0], A, row0, 0, K, tid);
  stage_tile<TBN>(sB[0], Bt, col0, 0, K, tid);

  for (int t = 0; t < NT; ++t) {
    __syncthreads();           // drains vmcnt(0): buffer staged last iter is ready
    int nb = (t + 1) & 1;
    if (t + 1 < NT) {          // issue next-tile STAGE before computing current (T3-minimum)
      stage_tile<TBM>(sA[nb], A, row0, (t + 1) << 6, K, tid);
      stage_tile<TBN>(sB[nb], Bt, col0, (t + 1) << 6, K, tid);
    }
    const unsigned short* pA = sA[t & 1];
    const unsigned short* pB = sB[t & 1];
#pragma unroll
    for (int kk = 0; kk < 2; ++kk) {
      int seg = (kk * 4 + hi) ^ lx;     // swizzled read seg
      f16x8 af[MF], bf[NF];
#pragma unroll
      for (int f = 0; f < MF; ++f) {
        int ra = wr * (MF * 16) + f * 16 + rsel;
        af[f] = *reinterpret_cast<const f16x8*>(&pA[ra * BK + seg * 8]);
      }
#pragma unroll
      for (int f = 0; f < NF; ++f) {
        int rn = wc * (NF * 16) + f * 16 + rsel;
        bf[f] = *reinterpret_cast<const f16x8*>(&pB[rn * BK + seg * 8]);
      }
#pragma unroll
      for (int mf = 0; mf < MF; ++mf)
#pragma unroll
        for (int nf = 0; nf < NF; ++nf)
          acc[mf][nf] = __builtin_amdgcn_mfma_f32_16x16x32_f16(af[mf], bf[nf], acc[mf][nf], 0, 0, 0);
    }
  }

  float scale = *sumptr / cnt;
#pragma unroll
  for (int mf = 0; mf < MF; ++mf) {
    long grow0 = row0 + wr * (MF * 16) + mf * 16 + hi * 4;
#pragma unroll
    for (int nf = 0; nf < NF; ++nf) {
      long gcol = col0 + wc * (NF * 16) + nf * 16 + rsel;
      float bv = HAS_BIAS ? bias[gcol] : 0.f;
#pragma unroll
      for (int r = 0; r < 4; ++r) {
        C[(grow0 + r) * (long)N + gcol] = acc[mf][nf][r] * scale + bv;
      }
    }
  }
}

// ---------------- launch ----------------
extern "C" void kernel_launch(void* const* d_in, const int* in_sizes, int n_in,
                              void* d_out, int out_size, void* d_ws, size_t ws_size,
                              hipStream_t stream) {
  const int* input_ids = (const int*)d_in[0];
  const float* embed   = (const float*)d_in[1];
  const float* layer_w = (const float*)d_in[2];
  const float* layer_b = (const float*)d_in[3];
  const float* ln_g    = (const float*)d_in[4];
  const float* ln_b    = (const float*)d_in[5];
  const float* final_g = (const float*)d_in[6];
  const float* final_b = (const float*)d_in[7];
  const float* head_w  = (const float*)d_in[8];
  float* out = (float*)d_out;

  char* ws = (char*)d_ws;
  size_t off = 0;
  auto take = [&](size_t bytes) -> void* {
    void* p = ws + off;
    off = (off + bytes + 255) & ~(size_t)255;
    return p;
  };
  float* sums        = (float*)take(16 * sizeof(float));          // [0..7]=layers, [8]=head
  unsigned short* Tl = (unsigned short*)take((size_t)H * H * 2);  // reused per layer
  unsigned short* Th = (unsigned short*)take((size_t)VOC * H * 2);
  float* hbuf        = (float*)take((size_t)MTOK * H * 4);
  float* ybuf        = (float*)take((size_t)MTOK * H * 4);
  unsigned short* act = (unsigned short*)take((size_t)MTOK * H * 2);
  (void)ws_size; (void)in_sizes; (void)n_in; (void)out_size;

  hipMemsetAsync(sums, 0, 16 * sizeof(float), stream);

  // all 8 layer abs-sums in one launch
  abssum_kernel<<<dim3(512, NL), 256, 0, stream>>>(layer_w, H * H, (long)H * H, sums);
  abssum_kernel<<<dim3(2048, 1), 256, 0, stream>>>(head_w, VOC * H, 0, sums + 8);

  quantize_kernel<<<4096, 256, 0, stream>>>(head_w, VOC * H, sums + 8, (float)((size_t)VOC * H), Th);

  gather_split_kernel<<<MTOK, 256, 0, stream>>>(input_ids, embed, hbuf, act);

  for (int l = 0; l < NL; ++l) {
    quantize_kernel<<<1024, 256, 0, stream>>>(layer_w + (size_t)l * H * H, H * H, sums + l,
                                              (float)(H * H), Tl);
    // 128x64 tile: grid = (2048/128)*(2048/64) = 512 blocks; LDS 48 KiB -> 3 blocks/CU
    gemm_t<128, 64, 4, 1, 2, 4, true><<<512, 256, 0, stream>>>(
        act, Tl, layer_b + (size_t)l * H, sums + l, (float)(H * H), ybuf, H, H, MTOK / 128);
    ln_kernel<<<MTOK, 256, 0, stream>>>(ybuf, hbuf, ln_g + (size_t)l * H, ln_b + (size_t)l * H,
                                        hbuf, act);
  }

  ln_kernel<<<MTOK, 256, 0, stream>>>(hbuf, nullptr, final_g, final_b, nullptr, act);

  // head: 128x128 tile: grid = 16*250 = 4000 blocks; LDS 64 KiB -> 2 blocks/CU
  gemm_t<128, 128, 2, 2, 4, 4, false><<<4000, 256, 0, stream>>>(
      act, Th, nullptr, sums + 8, (float)((size_t)VOC * H), out, VOC, H, MTOK / 128);
}

// Round 4
// 1442.123 us; speedup vs baseline: 1.4227x; 1.0250x over previous
//
#include <hip/hip_runtime.h>

// MockTritterModel: embedding -> 8x (ternary linear + residual + LN) -> LN -> ternary head
// Round 4: head GEMM moved to 256x256 8-wave 4-phase/counted-vmcnt schedule (T2+T3+T4+T5),
// derived waits: stage units A(0),B(0),B(1),A(1) one per phase, vmcnt(4) at phases 0,1,3.
// Layer GEMMs keep round-3 2-phase 128x64. Batched layer quantize. Numerics unchanged.

#define H 2048
#define MTOK 2048   // B*S
#define VOC 32000
#define NL 8
#define BK 64       // fp16 elems per K-tile (128 B per row)

typedef __attribute__((ext_vector_type(8))) _Float16 f16x8;
typedef __attribute__((ext_vector_type(4))) float f32x4;

__device__ __forceinline__ unsigned short f2h(float f) {
  _Float16 h = (_Float16)f;  // v_cvt_f16_f32, RNE
  union { _Float16 h; unsigned short u; } v; v.h = h;
  return v.u;
}

// ---------------- abs-sum reduction (for per-tensor mean|w|) ----------------
__global__ void abssum_kernel(const float* __restrict__ w, int n, long nstride,
                              float* __restrict__ out) {
  __shared__ float sbuf[4];
  const float* wp = w + (long)blockIdx.y * nstride;
  int tid = blockIdx.x * blockDim.x + threadIdx.x;
  int stride = gridDim.x * blockDim.x * 4;
  float s = 0.f;
  for (int i = tid * 4; i < n; i += stride) {
    float4 v = *reinterpret_cast<const float4*>(wp + i);
    s += fabsf(v.x) + fabsf(v.y) + fabsf(v.z) + fabsf(v.w);
  }
#pragma unroll
  for (int off = 32; off > 0; off >>= 1) s += __shfl_down(s, off);
  if ((threadIdx.x & 63) == 0) sbuf[threadIdx.x >> 6] = s;
  __syncthreads();
  if (threadIdx.x == 0) atomicAdd(out + blockIdx.y, sbuf[0] + sbuf[1] + sbuf[2] + sbuf[3]);
}

// ---------------- ternarize: T = fp16(clip(round(w/(s+1e-8)),-1,1)) ----------------
// gridDim.y tensors: w + y*nstride, scale sums[sbase+y], out T + y*tstride.
__global__ void quantize_kernel(const float* __restrict__ w, int n, long nstride,
                                const float* __restrict__ sums, int sbase, float cnt,
                                unsigned short* __restrict__ T, long tstride) {
  float scale = sums[sbase + blockIdx.y] / cnt;
  float spe = scale + 1e-8f;
  const float* wp = w + (long)blockIdx.y * nstride;
  unsigned short* tp = T + (long)blockIdx.y * tstride;
  int tid = blockIdx.x * blockDim.x + threadIdx.x;
  int stride = gridDim.x * blockDim.x * 4;
  for (int i = tid * 4; i < n; i += stride) {
    float4 v = *reinterpret_cast<const float4*>(wp + i);
    ushort4 t;
    t.x = f2h(fminf(fmaxf(rintf(v.x / spe), -1.f), 1.f));
    t.y = f2h(fminf(fmaxf(rintf(v.y / spe), -1.f), 1.f));
    t.z = f2h(fminf(fmaxf(rintf(v.z / spe), -1.f), 1.f));
    t.w = f2h(fminf(fmaxf(rintf(v.w / spe), -1.f), 1.f));
    *reinterpret_cast<ushort4*>(tp + i) = t;
  }
}

// ---------------- embedding gather + fp16 cast ----------------
__global__ void gather_split_kernel(const int* __restrict__ ids, const float* __restrict__ embed,
                                    float* __restrict__ h, unsigned short* __restrict__ act) {
  int t = blockIdx.x;
  long src = (long)ids[t] * H;
  long dst = (long)t * H;
  for (int c = threadIdx.x * 4; c < H; c += blockDim.x * 4) {
    float4 v = *reinterpret_cast<const float4*>(embed + src + c);
    *reinterpret_cast<float4*>(h + dst + c) = v;
    ushort4 u;
    u.x = f2h(v.x); u.y = f2h(v.y); u.z = f2h(v.z); u.w = f2h(v.w);
    *reinterpret_cast<ushort4*>(act + dst + c) = u;
  }
}

// ---------------- fused (optional residual) + LayerNorm + fp16 cast ----------------
__device__ __forceinline__ float block_sum(float v, float* sbuf) {
#pragma unroll
  for (int off = 32; off > 0; off >>= 1) v += __shfl_down(v, off);
  int lane = threadIdx.x & 63, w = threadIdx.x >> 6;
  if (lane == 0) sbuf[w] = v;
  __syncthreads();
  float r = sbuf[0] + sbuf[1] + sbuf[2] + sbuf[3];
  __syncthreads();
  return r;
}

__global__ void ln_kernel(const float* __restrict__ x_in, const float* __restrict__ resid,
                          const float* __restrict__ g, const float* __restrict__ b,
                          float* __restrict__ hout, unsigned short* __restrict__ act) {
  __shared__ float sbuf[4];
  int t = blockIdx.x;
  long base = (long)t * H;
  int c0 = threadIdx.x * 8;  // 256 threads * 8 = 2048 = H
  float x[8];
#pragma unroll
  for (int j = 0; j < 8; j += 4) {
    float4 v = *reinterpret_cast<const float4*>(x_in + base + c0 + j);
    x[j] = v.x; x[j + 1] = v.y; x[j + 2] = v.z; x[j + 3] = v.w;
  }
  if (resid != nullptr) {
#pragma unroll
    for (int j = 0; j < 8; j += 4) {
      float4 v = *reinterpret_cast<const float4*>(resid + base + c0 + j);
      x[j] += v.x; x[j + 1] += v.y; x[j + 2] += v.z; x[j + 3] += v.w;
    }
  }
  float s = 0.f;
#pragma unroll
  for (int j = 0; j < 8; ++j) s += x[j];
  s = block_sum(s, sbuf);
  float m = s * (1.f / H);
  float vs = 0.f;
#pragma unroll
  for (int j = 0; j < 8; ++j) { float d = x[j] - m; vs += d * d; }
  vs = block_sum(vs, sbuf);
  float r = 1.f / sqrtf(vs * (1.f / H) + 1e-5f);
  float o[8];
#pragma unroll
  for (int j = 0; j < 8; ++j) o[j] = (x[j] - m) * r * g[c0 + j] + b[c0 + j];
  if (hout != nullptr) {
#pragma unroll
    for (int j = 0; j < 8; j += 4) {
      float4 v; v.x = o[j]; v.y = o[j + 1]; v.z = o[j + 2]; v.w = o[j + 3];
      *reinterpret_cast<float4*>(hout + base + c0 + j) = v;
    }
  }
#pragma unroll
  for (int j = 0; j < 8; j += 4) {
    ushort4 u;
    u.x = f2h(o[j]); u.y = f2h(o[j + 1]); u.z = f2h(o[j + 2]); u.w = f2h(o[j + 3]);
    *reinterpret_cast<ushort4*>(act + base + c0 + j) = u;
  }
}

// ---------------- shared GEMM helpers ----------------
__device__ __forceinline__ void gll16(const void* g, void* l) {
  __builtin_amdgcn_global_load_lds((const __attribute__((address_space(1))) void*)g,
                                   (__attribute__((address_space(3))) void*)l, 16, 0, 0);
}

// ============ Round-3 2-phase 128x64 GEMM (layer path, known-good) ============
template <int ROWS>
__device__ __forceinline__ void stage_tile(unsigned short* sdst, const unsigned short* G,
                                           long row0, int k0, long ldk, int tid) {
  int wv = tid >> 6, lane = tid & 63;
  int c = lane & 7;            // seg slot within row (8 x 16B per 128B row)
  int r8 = lane >> 3;          // row within 8-row block
  int cs = c ^ r8;             // swizzled source seg
#pragma unroll
  for (int i = 0; i < ROWS / 32; ++i) {
    int blk = i * 4 + wv;                 // 1 KiB LDS blocks, 8 rows each
    int row = blk * 8 + r8;
    const unsigned short* g = G + (row0 + row) * ldk + (k0 + cs * 8);
    gll16((const void*)g, (void*)(sdst + blk * 512));
  }
}

template <int TBM, int TBN, int WR, int WC, int MF, int NF, bool HAS_BIAS>
__global__ __launch_bounds__(256)
void gemm_t(const unsigned short* __restrict__ A, const unsigned short* __restrict__ Bt,
            const float* __restrict__ bias, const float* __restrict__ sumptr, float cnt,
            float* __restrict__ C, int N, int K, int nrb) {
  __shared__ unsigned short sA[2][TBM * BK];
  __shared__ unsigned short sB[2][TBN * BK];
  int tid = threadIdx.x;
  int lane = tid & 63, wid = tid >> 6;
  int wr = wid / WC, wc = wid % WC;

  int nwg = gridDim.x;
  int bid = blockIdx.x;
  int chunk = nwg >> 3;
  int swz = (bid & 7) * chunk + (bid >> 3);
  int rb = swz % nrb, cbl = swz / nrb;
  long row0 = (long)rb * TBM;
  long col0 = (long)cbl * TBN;

  f32x4 acc[MF][NF] = {};

  int rsel = lane & 15;
  int hi = lane >> 4;
  int lx = lane & 7;

  int NT = K >> 6;
  stage_tile<TBM>(sA[0], A, row0, 0, K, tid);
  stage_tile<TBN>(sB[0], Bt, col0, 0, K, tid);

  for (int t = 0; t < NT; ++t) {
    __syncthreads();
    int nb = (t + 1) & 1;
    if (t + 1 < NT) {
      stage_tile<TBM>(sA[nb], A, row0, (t + 1) << 6, K, tid);
      stage_tile<TBN>(sB[nb], Bt, col0, (t + 1) << 6, K, tid);
    }
    const unsigned short* pA = sA[t & 1];
    const unsigned short* pB = sB[t & 1];
#pragma unroll
    for (int kk = 0; kk < 2; ++kk) {
      int seg = (kk * 4 + hi) ^ lx;
      f16x8 af[MF], bf[NF];
#pragma unroll
      for (int f = 0; f < MF; ++f) {
        int ra = wr * (MF * 16) + f * 16 + rsel;
        af[f] = *reinterpret_cast<const f16x8*>(&pA[ra * BK + seg * 8]);
      }
#pragma unroll
      for (int f = 0; f < NF; ++f) {
        int rn = wc * (NF * 16) + f * 16 + rsel;
        bf[f] = *reinterpret_cast<const f16x8*>(&pB[rn * BK + seg * 8]);
      }
#pragma unroll
      for (int mf = 0; mf < MF; ++mf)
#pragma unroll
        for (int nf = 0; nf < NF; ++nf)
          acc[mf][nf] = __builtin_amdgcn_mfma_f32_16x16x32_f16(af[mf], bf[nf], acc[mf][nf], 0, 0, 0);
    }
  }

  float scale = *sumptr / cnt;
#pragma unroll
  for (int mf = 0; mf < MF; ++mf) {
    long grow0 = row0 + wr * (MF * 16) + mf * 16 + hi * 4;
#pragma unroll
    for (int nf = 0; nf < NF; ++nf) {
      long gcol = col0 + wc * (NF * 16) + nf * 16 + rsel;
      float bv = HAS_BIAS ? bias[gcol] : 0.f;
#pragma unroll
      for (int r = 0; r < 4; ++r) {
        C[(grow0 + r) * (long)N + gcol] = acc[mf][nf][r] * scale + bv;
      }
    }
  }
}

// ============ Round-4 256x256 8-wave phase-split GEMM (head path) ============
// 8 waves as 2(M) x 4(N); per-wave output 128x64 = 8x4 fragments of 16x16.
// Per K-tile (BK=64): 4 phases (r,c) in order (0,0),(0,1),(1,1),(1,0); each phase:
// 12 ds_read_b128 + stage 1 unit (2 gll) + counted vmcnt + barrier + 16 MFMA + barrier.
// Stage units of tile t+1 during tile t: A(0)@p0, B(0)@p1, B(1)@p2, A(1)@p3.
// A(r) covers tile rows [r*64,r*64+64) u [128+r*64, 128+r*64+64)  (both wr groups).
// B(c) covers tile rows { 64k + c*32 + [0,32) : k=0..3 }          (all wc groups).
// Waits (2 loads/unit, in-order retire): vmcnt(4) at p0,p1,p3 -> unit needed by the
// NEXT phase is provably retired; none at p2. Epilogue tile: vmcnt(0) once.

__device__ __forceinline__ void stage_unitA(const unsigned short* G, long row0, int k0, long ldk,
                                            unsigned short* slot, int r, int widx, int lane) {
  int r8 = lane >> 3, cs = (lane & 7) ^ r8;
#pragma unroll
  for (int j = 0; j < 2; ++j) {
    int trow = j * 128 + r * 64 + widx * 8;   // 8-row group, wave-uniform
    const unsigned short* g = G + (row0 + trow + r8) * ldk + (k0 + cs * 8);
    gll16((const void*)g, (void*)(slot + trow * 64));
  }
}

__device__ __forceinline__ void stage_unitB(const unsigned short* G, long col0, int k0, long ldk,
                                            unsigned short* slot, int c, int widx, int lane) {
  int r8 = lane >> 3, cs = (lane & 7) ^ r8;
#pragma unroll
  for (int j = 0; j < 2; ++j) {
    int u = j * 8 + widx;
    int trow = (u >> 2) * 64 + c * 32 + (u & 3) * 8;
    const unsigned short* g = G + (col0 + trow + r8) * ldk + (k0 + cs * 8);
    gll16((const void*)g, (void*)(slot + trow * 64));
  }
}

template <int R, int C>
__device__ __forceinline__ void phase_read(const unsigned short* pA, const unsigned short* pB,
                                           int wr, int wc, int rsel, int hi, int lx,
                                           f16x8 (&af)[4][2], f16x8 (&bf)[2][2]) {
#pragma unroll
  for (int kk = 0; kk < 2; ++kk) {
    int seg = (kk * 4 + hi) ^ lx;
#pragma unroll
    for (int mf = 0; mf < 4; ++mf) {
      int ra = wr * 128 + R * 64 + mf * 16 + rsel;
      af[mf][kk] = *reinterpret_cast<const f16x8*>(&pA[ra * 64 + seg * 8]);
    }
#pragma unroll
    for (int nf = 0; nf < 2; ++nf) {
      int rb = wc * 64 + C * 32 + nf * 16 + rsel;
      bf[nf][kk] = *reinterpret_cast<const f16x8*>(&pB[rb * 64 + seg * 8]);
    }
  }
}

template <int R, int C>
__device__ __forceinline__ void phase_mfma(const f16x8 (&af)[4][2], const f16x8 (&bf)[2][2],
                                           f32x4 (&acc)[8][4]) {
#pragma unroll
  for (int kk = 0; kk < 2; ++kk)
#pragma unroll
    for (int mf = 0; mf < 4; ++mf)
#pragma unroll
      for (int nf = 0; nf < 2; ++nf)
        acc[R * 4 + mf][C * 2 + nf] = __builtin_amdgcn_mfma_f32_16x16x32_f16(
            af[mf][kk], bf[nf][kk], acc[R * 4 + mf][C * 2 + nf], 0, 0, 0);
}

#define PHASE(RR, CC, STAGE_STMT, DO_WAIT4)                                  \
  {                                                                          \
    f16x8 af[4][2], bf[2][2];                                                \
    phase_read<RR, CC>(pA, pB, wr, wc, rsel, hi, lx, af, bf);                \
    STAGE_STMT;                                                              \
    if (DO_WAIT4) asm volatile("s_waitcnt vmcnt(4)" ::: "memory");           \
    asm volatile("s_barrier" ::: "memory");                                  \
    asm volatile("s_waitcnt lgkmcnt(0)" ::: "memory");                       \
    __builtin_amdgcn_sched_barrier(0);                                       \
    __builtin_amdgcn_s_setprio(1);                                           \
    phase_mfma<RR, CC>(af, bf, acc);                                         \
    __builtin_amdgcn_s_setprio(0);                                           \
    asm volatile("s_barrier" ::: "memory");                                  \
  }

__global__ __launch_bounds__(512, 2)
void gemm256(const unsigned short* __restrict__ A, const unsigned short* __restrict__ Bt,
             const float* __restrict__ sumptr, float cnt,
             float* __restrict__ C, int N, int K, int nrb) {
  __shared__ unsigned short sA[2][256 * 64];
  __shared__ unsigned short sB[2][256 * 64];
  int tid = threadIdx.x, lane = tid & 63, widx = tid >> 6;
  int wr = widx >> 2, wc = widx & 3;
  int rsel = lane & 15, hi = lane >> 4, lx = lane & 7;

  int nwg = gridDim.x, bid = blockIdx.x, chunk = nwg >> 3;
  int swz = (bid & 7) * chunk + (bid >> 3);
  int rb = swz % nrb, cb = swz / nrb;
  long row0 = (long)rb * 256, col0 = (long)cb * 256;

  f32x4 acc[8][4] = {};

  int NT = K >> 6;
  // prologue: tile 0 units in first-use order
  stage_unitA(A, row0, 0, K, sA[0], 0, widx, lane);
  stage_unitB(Bt, col0, 0, K, sB[0], 0, widx, lane);
  stage_unitB(Bt, col0, 0, K, sB[0], 1, widx, lane);
  stage_unitA(A, row0, 0, K, sA[0], 1, widx, lane);
  asm volatile("s_waitcnt vmcnt(4)" ::: "memory");  // A(0),B(0) of tile0 retired
  asm volatile("s_barrier" ::: "memory");

  for (int t = 0; t < NT - 1; ++t) {
    const unsigned short* pA = sA[t & 1];
    const unsigned short* pB = sB[t & 1];
    unsigned short* qA = sA[(t + 1) & 1];
    unsigned short* qB = sB[(t + 1) & 1];
    int k1 = (t + 1) << 6;
    PHASE(0, 0, stage_unitA(A, row0, k1, K, qA, 0, widx, lane), true)
    PHASE(0, 1, stage_unitB(Bt, col0, k1, K, qB, 0, widx, lane), true)
    PHASE(1, 1, stage_unitB(Bt, col0, k1, K, qB, 1, widx, lane), false)
    PHASE(1, 0, stage_unitA(A, row0, k1, K, qA, 1, widx, lane), true)
  }

  // epilogue tile NT-1: everything staged; drain and compute (compiler inserts lgkm waits)
  asm volatile("s_waitcnt vmcnt(0)" ::: "memory");
  asm volatile("s_barrier" ::: "memory");
  {
    const unsigned short* pA = sA[(NT - 1) & 1];
    const unsigned short* pB = sB[(NT - 1) & 1];
    {
      f16x8 af[4][2], bf[2][2];
      phase_read<0, 0>(pA, pB, wr, wc, rsel, hi, lx, af, bf);
      phase_mfma<0, 0>(af, bf, acc);
    }
    {
      f16x8 af[4][2], bf[2][2];
      phase_read<0, 1>(pA, pB, wr, wc, rsel, hi, lx, af, bf);
      phase_mfma<0, 1>(af, bf, acc);
    }
    {
      f16x8 af[4][2], bf[2][2];
      phase_read<1, 1>(pA, pB, wr, wc, rsel, hi, lx, af, bf);
      phase_mfma<1, 1>(af, bf, acc);
    }
    {
      f16x8 af[4][2], bf[2][2];
      phase_read<1, 0>(pA, pB, wr, wc, rsel, hi, lx, af, bf);
      phase_mfma<1, 0>(af, bf, acc);
    }
  }

  float scale = *sumptr / cnt;
#pragma unroll
  for (int m = 0; m < 8; ++m) {
    long grow0 = row0 + wr * 128 + m * 16 + hi * 4;
#pragma unroll
    for (int n = 0; n < 4; ++n) {
      long gcol = col0 + wc * 64 + n * 16 + rsel;
#pragma unroll
      for (int r = 0; r < 4; ++r) {
        C[(grow0 + r) * (long)N + gcol] = acc[m][n][r] * scale;
      }
    }
  }
}

// ---------------- launch ----------------
extern "C" void kernel_launch(void* const* d_in, const int* in_sizes, int n_in,
                              void* d_out, int out_size, void* d_ws, size_t ws_size,
                              hipStream_t stream) {
  const int* input_ids = (const int*)d_in[0];
  const float* embed   = (const float*)d_in[1];
  const float* layer_w = (const float*)d_in[2];
  const float* layer_b = (const float*)d_in[3];
  const float* ln_g    = (const float*)d_in[4];
  const float* ln_b    = (const float*)d_in[5];
  const float* final_g = (const float*)d_in[6];
  const float* final_b = (const float*)d_in[7];
  const float* head_w  = (const float*)d_in[8];
  float* out = (float*)d_out;

  char* ws = (char*)d_ws;
  size_t off = 0;
  auto take = [&](size_t bytes) -> void* {
    void* p = ws + off;
    off = (off + bytes + 255) & ~(size_t)255;
    return p;
  };
  // batched layout needs ~240 MB; fall back to per-layer Tl if ws is smaller.
  size_t need_batched = (size_t)16 * 4 + (size_t)NL * H * H * 2 + (size_t)VOC * H * 2 +
                        2 * (size_t)MTOK * H * 4 + (size_t)MTOK * H * 2 + 6 * 256;
  bool batched = ws_size >= need_batched;

  float* sums        = (float*)take(16 * sizeof(float));
  unsigned short* Tl = (unsigned short*)take((batched ? (size_t)NL : 1) * H * H * 2);
  unsigned short* Th = (unsigned short*)take((size_t)VOC * H * 2);
  float* hbuf        = (float*)take((size_t)MTOK * H * 4);
  float* ybuf        = (float*)take((size_t)MTOK * H * 4);
  unsigned short* act = (unsigned short*)take((size_t)MTOK * H * 2);
  (void)in_sizes; (void)n_in; (void)out_size;

  hipMemsetAsync(sums, 0, 16 * sizeof(float), stream);

  abssum_kernel<<<dim3(512, NL), 256, 0, stream>>>(layer_w, H * H, (long)H * H, sums);
  abssum_kernel<<<dim3(2048, 1), 256, 0, stream>>>(head_w, VOC * H, 0, sums + 8);

  quantize_kernel<<<dim3(4096, 1), 256, 0, stream>>>(head_w, VOC * H, 0, sums, 8,
                                                     (float)((size_t)VOC * H), Th, 0);
  if (batched) {
    quantize_kernel<<<dim3(1024, NL), 256, 0, stream>>>(layer_w, H * H, (long)H * H, sums, 0,
                                                        (float)(H * H), Tl, (long)H * H);
  }

  gather_split_kernel<<<MTOK, 256, 0, stream>>>(input_ids, embed, hbuf, act);

  for (int l = 0; l < NL; ++l) {
    unsigned short* Tcur = Tl + (batched ? (size_t)l * H * H : 0);
    if (!batched) {
      quantize_kernel<<<dim3(1024, 1), 256, 0, stream>>>(layer_w + (size_t)l * H * H, H * H, 0,
                                                         sums, l, (float)(H * H), Tcur, 0);
    }
    gemm_t<128, 64, 4, 1, 2, 4, true><<<512, 256, 0, stream>>>(
        act, Tcur, layer_b + (size_t)l * H, sums + l, (float)(H * H), ybuf, H, H, MTOK / 128);
    ln_kernel<<<MTOK, 256, 0, stream>>>(ybuf, hbuf, ln_g + (size_t)l * H, ln_b + (size_t)l * H,
                                        hbuf, act);
  }

  ln_kernel<<<MTOK, 256, 0, stream>>>(hbuf, nullptr, final_g, final_b, nullptr, act);

  // head: 256x256 tiles -> grid (2048/256)*(32000/256) = 8*125 = 1000 (bijective XCD swizzle)
  gemm256<<<1000, 512, 0, stream>>>(act, Th, sums + 8, (float)((size_t)VOC * H), out, VOC, H,
                                    MTOK / 256);
}

// Round 5
// 1382.203 us; speedup vs baseline: 1.4844x; 1.0434x over previous
//
#include <hip/hip_runtime.h>

// MockTritterModel: embedding -> 8x (ternary linear + residual + LN) -> LN -> ternary head
// Round 5: counted-vmcnt 2-barrier GEMM loop (no drain-to-0 in main loop, no lgkmcnt(0)
// pinning -> compiler interleaves ds_read with MFMA). Each fragment read ONCE per K-tile
// (24 b128/wave for head, vs round-4's 48). Unified template for head (256x256, 8 waves)
// and layers (128x64, 4 waves, 3 blocks/CU). Numerics identical to rounds 2-4.

#define H 2048
#define MTOK 2048   // B*S
#define VOC 32000
#define NL 8
#define BK 64       // fp16 elems per K-tile (128 B per row)

typedef __attribute__((ext_vector_type(8))) _Float16 f16x8;
typedef __attribute__((ext_vector_type(4))) float f32x4;

__device__ __forceinline__ unsigned short f2h(float f) {
  _Float16 h = (_Float16)f;  // v_cvt_f16_f32, RNE
  union { _Float16 h; unsigned short u; } v; v.h = h;
  return v.u;
}

// ---------------- abs-sum reduction (for per-tensor mean|w|) ----------------
__global__ void abssum_kernel(const float* __restrict__ w, int n, long nstride,
                              float* __restrict__ out) {
  __shared__ float sbuf[4];
  const float* wp = w + (long)blockIdx.y * nstride;
  int tid = blockIdx.x * blockDim.x + threadIdx.x;
  int stride = gridDim.x * blockDim.x * 4;
  float s = 0.f;
  for (int i = tid * 4; i < n; i += stride) {
    float4 v = *reinterpret_cast<const float4*>(wp + i);
    s += fabsf(v.x) + fabsf(v.y) + fabsf(v.z) + fabsf(v.w);
  }
#pragma unroll
  for (int off = 32; off > 0; off >>= 1) s += __shfl_down(s, off);
  if ((threadIdx.x & 63) == 0) sbuf[threadIdx.x >> 6] = s;
  __syncthreads();
  if (threadIdx.x == 0) atomicAdd(out + blockIdx.y, sbuf[0] + sbuf[1] + sbuf[2] + sbuf[3]);
}

// ---------------- ternarize: T = fp16(clip(round(w/(s+1e-8)),-1,1)) ----------------
__global__ void quantize_kernel(const float* __restrict__ w, int n, long nstride,
                                const float* __restrict__ sums, int sbase, float cnt,
                                unsigned short* __restrict__ T, long tstride) {
  float scale = sums[sbase + blockIdx.y] / cnt;
  float spe = scale + 1e-8f;
  const float* wp = w + (long)blockIdx.y * nstride;
  unsigned short* tp = T + (long)blockIdx.y * tstride;
  int tid = blockIdx.x * blockDim.x + threadIdx.x;
  int stride = gridDim.x * blockDim.x * 4;
  for (int i = tid * 4; i < n; i += stride) {
    float4 v = *reinterpret_cast<const float4*>(wp + i);
    ushort4 t;
    t.x = f2h(fminf(fmaxf(rintf(v.x / spe), -1.f), 1.f));
    t.y = f2h(fminf(fmaxf(rintf(v.y / spe), -1.f), 1.f));
    t.z = f2h(fminf(fmaxf(rintf(v.z / spe), -1.f), 1.f));
    t.w = f2h(fminf(fmaxf(rintf(v.w / spe), -1.f), 1.f));
    *reinterpret_cast<ushort4*>(tp + i) = t;
  }
}

// ---------------- embedding gather + fp16 cast ----------------
__global__ void gather_split_kernel(const int* __restrict__ ids, const float* __restrict__ embed,
                                    float* __restrict__ h, unsigned short* __restrict__ act) {
  int t = blockIdx.x;
  long src = (long)ids[t] * H;
  long dst = (long)t * H;
  for (int c = threadIdx.x * 4; c < H; c += blockDim.x * 4) {
    float4 v = *reinterpret_cast<const float4*>(embed + src + c);
    *reinterpret_cast<float4*>(h + dst + c) = v;
    ushort4 u;
    u.x = f2h(v.x); u.y = f2h(v.y); u.z = f2h(v.z); u.w = f2h(v.w);
    *reinterpret_cast<ushort4*>(act + dst + c) = u;
  }
}

// ---------------- fused (optional residual) + LayerNorm + fp16 cast ----------------
__device__ __forceinline__ float block_sum(float v, float* sbuf) {
#pragma unroll
  for (int off = 32; off > 0; off >>= 1) v += __shfl_down(v, off);
  int lane = threadIdx.x & 63, w = threadIdx.x >> 6;
  if (lane == 0) sbuf[w] = v;
  __syncthreads();
  float r = sbuf[0] + sbuf[1] + sbuf[2] + sbuf[3];
  __syncthreads();
  return r;
}

__global__ void ln_kernel(const float* __restrict__ x_in, const float* __restrict__ resid,
                          const float* __restrict__ g, const float* __restrict__ b,
                          float* __restrict__ hout, unsigned short* __restrict__ act) {
  __shared__ float sbuf[4];
  int t = blockIdx.x;
  long base = (long)t * H;
  int c0 = threadIdx.x * 8;  // 256 threads * 8 = 2048 = H
  float x[8];
#pragma unroll
  for (int j = 0; j < 8; j += 4) {
    float4 v = *reinterpret_cast<const float4*>(x_in + base + c0 + j);
    x[j] = v.x; x[j + 1] = v.y; x[j + 2] = v.z; x[j + 3] = v.w;
  }
  if (resid != nullptr) {
#pragma unroll
    for (int j = 0; j < 8; j += 4) {
      float4 v = *reinterpret_cast<const float4*>(resid + base + c0 + j);
      x[j] += v.x; x[j + 1] += v.y; x[j + 2] += v.z; x[j + 3] += v.w;
    }
  }
  float s = 0.f;
#pragma unroll
  for (int j = 0; j < 8; ++j) s += x[j];
  s = block_sum(s, sbuf);
  float m = s * (1.f / H);
  float vs = 0.f;
#pragma unroll
  for (int j = 0; j < 8; ++j) { float d = x[j] - m; vs += d * d; }
  vs = block_sum(vs, sbuf);
  float r = 1.f / sqrtf(vs * (1.f / H) + 1e-5f);
  float o[8];
#pragma unroll
  for (int j = 0; j < 8; ++j) o[j] = (x[j] - m) * r * g[c0 + j] + b[c0 + j];
  if (hout != nullptr) {
#pragma unroll
    for (int j = 0; j < 8; j += 4) {
      float4 v; v.x = o[j]; v.y = o[j + 1]; v.z = o[j + 2]; v.w = o[j + 3];
      *reinterpret_cast<float4*>(hout + base + c0 + j) = v;
    }
  }
#pragma unroll
  for (int j = 0; j < 8; j += 4) {
    ushort4 u;
    u.x = f2h(o[j]); u.y = f2h(o[j + 1]); u.z = f2h(o[j + 2]); u.w = f2h(o[j + 3]);
    *reinterpret_cast<ushort4*>(act + base + c0 + j) = u;
  }
}

// ---------------- GEMM: C[m,n] = scale * sum_k A[m,k] * Bt[n,k] (+ bias[n]) ----------------
__device__ __forceinline__ void gll16(const void* g, void* l) {
  __builtin_amdgcn_global_load_lds((const __attribute__((address_space(1))) void*)g,
                                   (__attribute__((address_space(3))) void*)l, 16, 0, 0);
}

// Stage a [ROWS][64] fp16 tile into linear LDS with XOR-swizzled global source
// (rule #21: linear dest, inverse-swz source, same XOR on read).
// LDS slot (row, c) holds global seg (row, c ^ (row & 7)).
template <int ROWS, int NTH>
__device__ __forceinline__ void stage_tile(unsigned short* sdst, const unsigned short* G,
                                           long row0, int k0, long ldk, int tid) {
  constexpr int WPB = NTH / 64;   // waves per block
  int wv = tid >> 6, lane = tid & 63;
  int r8 = lane >> 3;             // row within 8-row (1 KiB) block
  int cs = (lane & 7) ^ r8;       // swizzled source seg
#pragma unroll
  for (int i = 0; i < (ROWS / 8) / WPB; ++i) {
    int blk = i * WPB + wv;
    int row = blk * 8 + r8;
    const unsigned short* g = G + (row0 + row) * ldk + (k0 + cs * 8);
    gll16((const void*)g, (void*)(sdst + blk * 512));  // lane writes blk*1024B + lane*16B
  }
}

// Counted-vmcnt 2-barrier double-buffered loop. Per iter:
//   stage(t+1) ; vmcnt(L) [retires tile-t loads, issued one full tile ago -> near-free]
//   s_barrier ; reads+MFMA of tile t (compiler-interleaved lgkm) ; s_barrier
// Barrier#2 guarantees buf[cur] fully read before next iter restages it.
template <int TBM, int TBN, int NTH, int WC, int MF, int NF, bool HAS_BIAS>
__global__ __launch_bounds__(NTH, NTH == 512 ? 2 : 3)
void gemm_cnt(const unsigned short* __restrict__ A, const unsigned short* __restrict__ Bt,
              const float* __restrict__ bias, const float* __restrict__ sumptr, float cnt,
              float* __restrict__ C, int N, int K, int nrb) {
  __shared__ unsigned short sA[2][TBM * BK];
  __shared__ unsigned short sB[2][TBN * BK];
  constexpr int WAITN = (TBM + TBN) / (NTH / 8);   // loads per thread per K-tile
  static_assert(WAITN == 6 || WAITN == 8, "unsupported wait count");

  int tid = threadIdx.x, lane = tid & 63, wid = tid >> 6;
  int wr = wid / WC, wc = wid % WC;
  int rsel = lane & 15, hi = lane >> 4, lx = lane & 7;

  // bijective XCD swizzle (grid % 8 == 0), row-block-fastest mapping
  int nwg = gridDim.x, bid = blockIdx.x, chunk = nwg >> 3;
  int swz = (bid & 7) * chunk + (bid >> 3);
  int rb = swz % nrb, cbl = swz / nrb;
  long row0 = (long)rb * TBM, col0 = (long)cbl * TBN;

  f32x4 acc[MF][NF] = {};
  int NT = K >> 6;

  stage_tile<TBM, NTH>(sA[0], A, row0, 0, K, tid);
  stage_tile<TBN, NTH>(sB[0], Bt, col0, 0, K, tid);

  for (int t = 0; t < NT; ++t) {
    int cur = t & 1;
    if (t + 1 < NT) {
      stage_tile<TBM, NTH>(sA[cur ^ 1], A, row0, (t + 1) << 6, K, tid);
      stage_tile<TBN, NTH>(sB[cur ^ 1], Bt, col0, (t + 1) << 6, K, tid);
      if constexpr (WAITN == 8) asm volatile("s_waitcnt vmcnt(8)" ::: "memory");
      else                      asm volatile("s_waitcnt vmcnt(6)" ::: "memory");
    } else {
      asm volatile("s_waitcnt vmcnt(0)" ::: "memory");
    }
    asm volatile("s_barrier" ::: "memory");

    const unsigned short* pA = sA[cur];
    const unsigned short* pB = sB[cur];
#pragma unroll
    for (int kk = 0; kk < 2; ++kk) {
      int seg = (kk * 4 + hi) ^ lx;
      f16x8 af[MF], bf[NF];
#pragma unroll
      for (int mf = 0; mf < MF; ++mf)
        af[mf] = *reinterpret_cast<const f16x8*>(
            &pA[(wr * (MF * 16) + mf * 16 + rsel) * BK + seg * 8]);
#pragma unroll
      for (int nf = 0; nf < NF; ++nf)
        bf[nf] = *reinterpret_cast<const f16x8*>(
            &pB[(wc * (NF * 16) + nf * 16 + rsel) * BK + seg * 8]);
#pragma unroll
      for (int mf = 0; mf < MF; ++mf)
#pragma unroll
        for (int nf = 0; nf < NF; ++nf)
          acc[mf][nf] = __builtin_amdgcn_mfma_f32_16x16x32_f16(af[mf], bf[nf], acc[mf][nf], 0, 0, 0);
    }
    asm volatile("s_barrier" ::: "memory");
  }

  float scale = *sumptr / cnt;
#pragma unroll
  for (int mf = 0; mf < MF; ++mf) {
    long grow0 = row0 + wr * (MF * 16) + mf * 16 + hi * 4;
#pragma unroll
    for (int nf = 0; nf < NF; ++nf) {
      long gcol = col0 + wc * (NF * 16) + nf * 16 + rsel;
      float bv = HAS_BIAS ? bias[gcol] : 0.f;
#pragma unroll
      for (int r = 0; r < 4; ++r) {
        C[(grow0 + r) * (long)N + gcol] = acc[mf][nf][r] * scale + bv;
      }
    }
  }
}

// ---------------- launch ----------------
extern "C" void kernel_launch(void* const* d_in, const int* in_sizes, int n_in,
                              void* d_out, int out_size, void* d_ws, size_t ws_size,
                              hipStream_t stream) {
  const int* input_ids = (const int*)d_in[0];
  const float* embed   = (const float*)d_in[1];
  const float* layer_w = (const float*)d_in[2];
  const float* layer_b = (const float*)d_in[3];
  const float* ln_g    = (const float*)d_in[4];
  const float* ln_b    = (const float*)d_in[5];
  const float* final_g = (const float*)d_in[6];
  const float* final_b = (const float*)d_in[7];
  const float* head_w  = (const float*)d_in[8];
  float* out = (float*)d_out;

  char* ws = (char*)d_ws;
  size_t off = 0;
  auto take = [&](size_t bytes) -> void* {
    void* p = ws + off;
    off = (off + bytes + 255) & ~(size_t)255;
    return p;
  };
  size_t need_batched = (size_t)16 * 4 + (size_t)NL * H * H * 2 + (size_t)VOC * H * 2 +
                        2 * (size_t)MTOK * H * 4 + (size_t)MTOK * H * 2 + 6 * 256;
  bool batched = ws_size >= need_batched;

  float* sums        = (float*)take(16 * sizeof(float));
  unsigned short* Tl = (unsigned short*)take((batched ? (size_t)NL : 1) * H * H * 2);
  unsigned short* Th = (unsigned short*)take((size_t)VOC * H * 2);
  float* hbuf        = (float*)take((size_t)MTOK * H * 4);
  float* ybuf        = (float*)take((size_t)MTOK * H * 4);
  unsigned short* act = (unsigned short*)take((size_t)MTOK * H * 2);
  (void)in_sizes; (void)n_in; (void)out_size;

  hipMemsetAsync(sums, 0, 16 * sizeof(float), stream);

  abssum_kernel<<<dim3(512, NL), 256, 0, stream>>>(layer_w, H * H, (long)H * H, sums);
  abssum_kernel<<<dim3(2048, 1), 256, 0, stream>>>(head_w, VOC * H, 0, sums + 8);

  quantize_kernel<<<dim3(4096, 1), 256, 0, stream>>>(head_w, VOC * H, 0, sums, 8,
                                                     (float)((size_t)VOC * H), Th, 0);
  if (batched) {
    quantize_kernel<<<dim3(1024, NL), 256, 0, stream>>>(layer_w, H * H, (long)H * H, sums, 0,
                                                        (float)(H * H), Tl, (long)H * H);
  }

  gather_split_kernel<<<MTOK, 256, 0, stream>>>(input_ids, embed, hbuf, act);

  for (int l = 0; l < NL; ++l) {
    unsigned short* Tcur = Tl + (batched ? (size_t)l * H * H : 0);
    if (!batched) {
      quantize_kernel<<<dim3(1024, 1), 256, 0, stream>>>(layer_w + (size_t)l * H * H, H * H, 0,
                                                         sums, l, (float)(H * H), Tcur, 0);
    }
    // 128x64 tile, 4 waves (wr 0..3), 48 KiB LDS -> 3 blocks/CU; grid 512
    gemm_cnt<128, 64, 256, 1, 2, 4, true><<<512, 256, 0, stream>>>(
        act, Tcur, layer_b + (size_t)l * H, sums + l, (float)(H * H), ybuf, H, H, MTOK / 128);
    ln_kernel<<<MTOK, 256, 0, stream>>>(ybuf, hbuf, ln_g + (size_t)l * H, ln_b + (size_t)l * H,
                                        hbuf, act);
  }

  ln_kernel<<<MTOK, 256, 0, stream>>>(hbuf, nullptr, final_g, final_b, nullptr, act);

  // head: 256x256 tile, 8 waves as 2(M)x4(N), 128 KiB LDS; grid 8*125 = 1000
  gemm_cnt<256, 256, 512, 4, 8, 4, false><<<1000, 512, 0, stream>>>(
      act, Th, nullptr, sums + 8, (float)((size_t)VOC * H), out, VOC, H, MTOK / 256);
}